// Round 10
// baseline (4767.088 us; speedup 1.0000x reference)
//
#include <hip/hip_runtime.h>

#define NN 50000
#define NE 800000
#define MUL 32
#define RAD 8
#define FC 64

typedef float f16v __attribute__((ext_vector_type(16)));

__device__ __forceinline__ float gelu_t(float x) {
    // jax.nn.gelu approximate=True
    float x3 = x * x * x;
    float t = 0.7978845608028654f * (x + 0.044715f * x3);
    float e = __expf(2.0f * t);
    return 0.5f * x * (2.0f - 2.0f / (e + 1.0f));
}

// Pre-transpose mlp_w0 (8x64 -> 64x8) and wp0..3 (64x32 -> 4 x 32x64).
__global__ void k_transpose(const float* __restrict__ mlp_w0,
                            const float* __restrict__ wp0, const float* __restrict__ wp1,
                            const float* __restrict__ wp2, const float* __restrict__ wp3,
                            float* __restrict__ w0T, float* __restrict__ wpT) {
    int t = threadIdx.x;
    for (int idx = t; idx < FC * RAD; idx += 256) {
        int k = idx >> 3, u = idx & 7;
        w0T[idx] = mlp_w0[u * FC + k];
    }
    const float* wps[4] = {wp0, wp1, wp2, wp3};
    for (int p = 0; p < 4; p++) {
        for (int idx = t; idx < MUL * FC; idx += 256) {
            int c = idx >> 6, k = idx & 63;
            wpT[p * (MUL * FC) + idx] = wps[p][k * MUL + c];
        }
    }
}

__global__ __launch_bounds__(256) void k_node_pre(
        const float* __restrict__ node_s, const float* __restrict__ node_v,
        const float* __restrict__ W_feat0, const float* __restrict__ W_feat1,
        float* __restrict__ f0, float* __restrict__ f1) {
    __shared__ float w0[MUL * MUL], w1[MUL * MUL];
    int t = threadIdx.x;
    for (int i = t; i < MUL * MUL; i += 256) { w0[i] = W_feat0[i]; w1[i] = W_feat1[i]; }
    __syncthreads();
    int v = t & 31;
    int n = blockIdx.x * 8 + (t >> 5);
    if (n >= NN) return;
    const float invm = 0.17677669529663687f;  // 1/sqrt(32)
    float a0 = 0.f, ax = 0.f, ay = 0.f, az = 0.f;
    const float* srow = node_s + (size_t)n * MUL;
    const float* vrow = node_v + (size_t)n * MUL * 3;
#pragma unroll
    for (int u = 0; u < MUL; u++) {
        float ws = w0[u * MUL + v];
        a0 += srow[u] * ws;
        float wv = w1[u * MUL + v];
        ax += vrow[u * 3 + 0] * wv;
        ay += vrow[u * 3 + 1] * wv;
        az += vrow[u * 3 + 2] * wv;
    }
    f0[n * MUL + v] = a0 * invm;
    f1[n * 96 + v * 3 + 0] = ax * invm;
    f1[n * 96 + v * 3 + 1] = ay * invm;
    f1[n * 96 + v * 3 + 2] = az * invm;
}

// ---- CSR build: histogram -> single-block scan -> fill ----
__global__ __launch_bounds__(256) void k_hist(const int* __restrict__ edge_dst,
                                              unsigned* __restrict__ counts) {
    int e = blockIdx.x * 256 + threadIdx.x;
    if (e < NE) atomicAdd(&counts[edge_dst[e]], 1u);
}

__global__ __launch_bounds__(1024) void k_scan(const unsigned* __restrict__ counts,
                                               unsigned* __restrict__ offsets,
                                               unsigned* __restrict__ cursor) {
    __shared__ unsigned part[1024];
    int t = threadIdx.x;
    const int PER = 49;  // 49*1024 = 50176 >= 50000
    int b0 = t * PER, b1 = b0 + PER;
    if (b0 > NN) b0 = NN;
    if (b1 > NN) b1 = NN;
    unsigned s = 0;
    for (int i = b0; i < b1; i++) s += counts[i];
    part[t] = s;
    __syncthreads();
    for (int d = 1; d < 1024; d <<= 1) {
        unsigned v = (t >= d) ? part[t - d] : 0u;
        __syncthreads();
        part[t] += v;
        __syncthreads();
    }
    unsigned off = (t > 0) ? part[t - 1] : 0u;
    for (int i = b0; i < b1; i++) {
        offsets[i] = off;
        cursor[i] = off;
        off += counts[i];
    }
    if (t == 1023) offsets[NN] = part[1023];
}

__global__ __launch_bounds__(256) void k_fill(const int* __restrict__ edge_dst,
                                              unsigned* __restrict__ cursor,
                                              unsigned* __restrict__ eid) {
    int e = blockIdx.x * 256 + threadIdx.x;
    if (e < NE) {
        unsigned pos = atomicAdd(&cursor[edge_dst[e]], 1u);
        eid[pos] = (unsigned)e;
    }
}

// ---- Pass A: per-edge MLP + projections -> 256 fully-expanded SoA planes ----
// plane p * CHP + ii:
//   [0,32)    p0   = w0*e0*s0
//   [32,64)   p3   = w3*dot(e1,sh1)/sqrt3
//   [64,160)  p1   : plane 64 + c*3+d  = (w1*e0)*sh1[d]
//   [160,256) p2   : plane 160 + c*3+d = (w2*s0)*e1[c][d]
// CHP = chunk+16 floats (odd 64B-sector stride: breaks HBM channel aliasing).
__global__ __launch_bounds__(256, 2) void k_edgeA(
        int lo, int n_chunk, int CHP,
        const unsigned* __restrict__ eid,
        const float* __restrict__ edge_scalar, const float* __restrict__ sh0,
        const float* __restrict__ sh1, const int* __restrict__ edge_src,
        const float* __restrict__ w0T, const float* __restrict__ mlp_w1,
        const float* __restrict__ wpT, const float* __restrict__ f0,
        const float* __restrict__ f1, float* __restrict__ rec) {
    int ii = blockIdx.x * 256 + threadIdx.x;
    if (ii >= n_chunk) return;
    int e = (int)eid[lo + ii];

    float4 xa = ((const float4*)edge_scalar)[e * 2 + 0];
    float4 xb = ((const float4*)edge_scalar)[e * 2 + 1];

    const float inv_r = 0.35355339059327373f;  // 1/sqrt(8)
    const float inv_f = 0.125f;                // 1/sqrt(64)

    f16v h0 = 0.f, h1 = 0.f, h2 = 0.f, h3 = 0.f;

    for (int k = 0; k < FC; k++) {
        const float4* w0r = (const float4*)(w0T + k * RAD);
        float4 wa = w0r[0], wb = w0r[1];
        float a = xa.x * wa.x + xa.y * wa.y + xa.z * wa.z + xa.w * wa.w +
                  xb.x * wb.x + xb.y * wb.y + xb.z * wb.z + xb.w * wb.w;
        a = gelu_t(a * inv_r);
        const float* w1r = mlp_w1 + k * FC;
#pragma unroll
        for (int i = 0; i < 16; i++) h0[i] += a * w1r[i];
#pragma unroll
        for (int i = 0; i < 16; i++) h1[i] += a * w1r[16 + i];
#pragma unroll
        for (int i = 0; i < 16; i++) h2[i] += a * w1r[32 + i];
#pragma unroll
        for (int i = 0; i < 16; i++) h3[i] += a * w1r[48 + i];
    }
#pragma unroll
    for (int i = 0; i < 16; i++) {
        h0[i] = gelu_t(h0[i] * inv_f);
        h1[i] = gelu_t(h1[i] * inv_f);
        h2[i] = gelu_t(h2[i] * inv_f);
        h3[i] = gelu_t(h3[i] * inv_f);
    }

    int src = edge_src[e];
    float s0 = sh0[e];
    float shx = sh1[e * 3 + 0], shy = sh1[e * 3 + 1], shz = sh1[e * 3 + 2];
    const float* F0 = f0 + (size_t)src * MUL;
    const float* F1 = f1 + (size_t)src * 96;
    const float inv3 = 0.5773502691896258f;  // 1/sqrt(3)

    for (int c = 0; c < MUL; c++) {
        const float* p0w = wpT + 0 * (MUL * FC) + c * FC;
        const float* p1w = wpT + 1 * (MUL * FC) + c * FC;
        const float* p2w = wpT + 2 * (MUL * FC) + c * FC;
        const float* p3w = wpT + 3 * (MUL * FC) + c * FC;
        float w0a = 0.f, w1a = 0.f, w2a = 0.f, w3a = 0.f;
#pragma unroll
        for (int i = 0; i < 16; i++) {
            float h = h0[i];
            w0a += h * p0w[i]; w1a += h * p1w[i]; w2a += h * p2w[i]; w3a += h * p3w[i];
        }
#pragma unroll
        for (int i = 0; i < 16; i++) {
            float h = h1[i];
            w0a += h * p0w[16 + i]; w1a += h * p1w[16 + i]; w2a += h * p2w[16 + i]; w3a += h * p3w[16 + i];
        }
#pragma unroll
        for (int i = 0; i < 16; i++) {
            float h = h2[i];
            w0a += h * p0w[32 + i]; w1a += h * p1w[32 + i]; w2a += h * p2w[32 + i]; w3a += h * p3w[32 + i];
        }
#pragma unroll
        for (int i = 0; i < 16; i++) {
            float h = h3[i];
            w0a += h * p0w[48 + i]; w1a += h * p1w[48 + i]; w2a += h * p2w[48 + i]; w3a += h * p3w[48 + i];
        }
        w0a *= inv_f; w1a *= inv_f; w2a *= inv_f; w3a *= inv_f;

        float e0c = F0[c];
        float e1x = F1[c * 3 + 0], e1y = F1[c * 3 + 1], e1z = F1[c * 3 + 2];
        float dot = e1x * shx + e1y * shy + e1z * shz;
        float w1e = w1a * e0c;
        float p2s = w2a * s0;

        rec[(size_t)(c)             * CHP + ii] = w0a * e0c * s0;
        rec[(size_t)(32 + c)        * CHP + ii] = w3a * dot * inv3;
        rec[(size_t)(64 + c * 3 + 0)  * CHP + ii] = w1e * shx;
        rec[(size_t)(64 + c * 3 + 1)  * CHP + ii] = w1e * shy;
        rec[(size_t)(64 + c * 3 + 2)  * CHP + ii] = w1e * shz;
        rec[(size_t)(160 + c * 3 + 0) * CHP + ii] = p2s * e1x;
        rec[(size_t)(160 + c * 3 + 1) * CHP + ii] = p2s * e1y;
        rec[(size_t)(160 + c * 3 + 2) * CHP + ii] = p2s * e1z;
    }
}

// ---- Pass B: pure streaming segment-sum per (dst, c); no gathers, no atomics ----
__global__ __launch_bounds__(256) void k_gatherB(
        int lo, int hi, int CHP, int first,
        const unsigned* __restrict__ offsets,
        const float* __restrict__ rec,
        float* __restrict__ n0, float* __restrict__ n1) {
    // XCD-bijective block swizzle: contiguous dst chunks per XCD (L2 locality)
    int nwg = gridDim.x;
    int orig = blockIdx.x;
    int q = nwg >> 3, r = nwg & 7;
    int xcd = orig & 7, idx = orig >> 3;
    int wg = (xcd < r ? xcd * (q + 1) : r * (q + 1) + (xcd - r) * q) + idx;

    int g = wg * 256 + threadIdx.x;
    int dst = g >> 5, c = g & 31;
    if (dst >= NN) return;
    int a = (int)offsets[dst];
    int b = (int)offsets[dst + 1];
    if (a < lo) a = lo;
    if (b > hi) b = hi;
    if (a >= b) return;

    const float* q0  = rec + (size_t)(c)              * CHP - lo;
    const float* q3  = rec + (size_t)(32 + c)         * CHP - lo;
    const float* q10 = rec + (size_t)(64 + c * 3 + 0)  * CHP - lo;
    const float* q11 = rec + (size_t)(64 + c * 3 + 1)  * CHP - lo;
    const float* q12 = rec + (size_t)(64 + c * 3 + 2)  * CHP - lo;
    const float* q20 = rec + (size_t)(160 + c * 3 + 0) * CHP - lo;
    const float* q21 = rec + (size_t)(160 + c * 3 + 1) * CHP - lo;
    const float* q22 = rec + (size_t)(160 + c * 3 + 2) * CHP - lo;

    float s_0 = 0.f, s_3 = 0.f;
    float s10 = 0.f, s11 = 0.f, s12 = 0.f;
    float s20 = 0.f, s21 = 0.f, s22 = 0.f;
#pragma unroll 2
    for (int i = a; i < b; i++) {
        s_0 += q0[i];  s_3 += q3[i];
        s10 += q10[i]; s11 += q11[i]; s12 += q12[i];
        s20 += q20[i]; s21 += q21[i]; s22 += q22[i];
    }
    float* O0 = n0 + (size_t)dst * 64;
    float* O1 = n1 + (size_t)dst * 192;
    if (first) {
        O0[c]      = s_0;
        O0[32 + c] = s_3;
        O1[c * 3 + 0] = s10; O1[c * 3 + 1] = s11; O1[c * 3 + 2] = s12;
        O1[96 + c * 3 + 0] = s20; O1[96 + c * 3 + 1] = s21; O1[96 + c * 3 + 2] = s22;
    } else {
        O0[c]      += s_0;
        O0[32 + c] += s_3;
        O1[c * 3 + 0] += s10; O1[c * 3 + 1] += s11; O1[c * 3 + 2] += s12;
        O1[96 + c * 3 + 0] += s20; O1[96 + c * 3 + 1] += s21; O1[96 + c * 3 + 2] += s22;
    }
}

__global__ __launch_bounds__(256) void k_out(
        const float* __restrict__ node_s, const float* __restrict__ node_v,
        const float* __restrict__ W_self0, const float* __restrict__ W_self1,
        const float* __restrict__ W_out0, const float* __restrict__ W_out1,
        const float* __restrict__ n0, const float* __restrict__ n1,
        float* __restrict__ out) {
    __shared__ float ws0[MUL * MUL], ws1[MUL * MUL], wo0[64 * MUL], wo1[64 * MUL];
    int t = threadIdx.x;
    for (int i = t; i < MUL * MUL; i += 256) { ws0[i] = W_self0[i]; ws1[i] = W_self1[i]; }
    for (int i = t; i < 64 * MUL; i += 256) { wo0[i] = W_out0[i]; wo1[i] = W_out1[i]; }
    __syncthreads();
    int v = t & 31;
    int n = blockIdx.x * 8 + (t >> 5);
    if (n >= NN) return;
    const float invm = 0.17677669529663687f;       // 1/sqrt(32)
    const float scale_c = 0.125f * 0.25f;          // 1/sqrt(64) * 1/sqrt(16)
    const float cc = 0.9238795325112867f;          // cos(pi/8)
    const float ss = 0.3826834323650898f;          // sin(pi/8)

    float s0 = 0.f, sx = 0.f, sy = 0.f, sz = 0.f;
    const float* srow = node_s + (size_t)n * MUL;
    const float* vrow = node_v + (size_t)n * 96;
#pragma unroll
    for (int u = 0; u < MUL; u++) {
        float w = ws0[u * MUL + v];
        s0 += srow[u] * w;
        float w2 = ws1[u * MUL + v];
        sx += vrow[u * 3 + 0] * w2;
        sy += vrow[u * 3 + 1] * w2;
        sz += vrow[u * 3 + 2] * w2;
    }
    float c0 = 0.f, cx = 0.f, cy = 0.f, cz = 0.f;
    const float* nr0 = n0 + (size_t)n * 64;
    const float* nr1 = n1 + (size_t)n * 192;
#pragma unroll
    for (int u = 0; u < 64; u++) {
        float w = wo0[u * MUL + v];
        c0 += nr0[u] * w;
        float w2 = wo1[u * MUL + v];
        cx += nr1[u * 3 + 0] * w2;
        cy += nr1[u * 3 + 1] * w2;
        cz += nr1[u * 3 + 2] * w2;
    }
    float* orow = out + (size_t)n * 128;
    orow[v] = cc * s0 * invm + ss * c0 * scale_c;
    orow[32 + v * 3 + 0] = cc * sx * invm + ss * cx * scale_c;
    orow[32 + v * 3 + 1] = cc * sy * invm + ss * cy * scale_c;
    orow[32 + v * 3 + 2] = cc * sz * invm + ss * cz * scale_c;
}

extern "C" void kernel_launch(void* const* d_in, const int* in_sizes, int n_in,
                              void* d_out, int out_size, void* d_ws, size_t ws_size,
                              hipStream_t stream) {
    const float* node_s      = (const float*)d_in[0];
    const float* node_v      = (const float*)d_in[1];
    const float* sh0         = (const float*)d_in[2];
    const float* sh1         = (const float*)d_in[3];
    const float* edge_scalar = (const float*)d_in[4];
    const int*   edge_src    = (const int*)d_in[5];
    const int*   edge_dst    = (const int*)d_in[6];
    const float* W_feat0     = (const float*)d_in[7];
    const float* W_self0     = (const float*)d_in[8];
    const float* W_feat1     = (const float*)d_in[9];
    const float* W_self1     = (const float*)d_in[10];
    const float* mlp_w0      = (const float*)d_in[11];
    const float* mlp_w1      = (const float*)d_in[12];
    const float* wp0         = (const float*)d_in[13];
    const float* wp1         = (const float*)d_in[14];
    const float* wp2         = (const float*)d_in[15];
    const float* wp3         = (const float*)d_in[16];
    const float* W_out0      = (const float*)d_in[17];
    const float* W_out1      = (const float*)d_in[18];

    // workspace layout (floats/u32 are both 4B)
    float* ws  = (float*)d_ws;
    float*    f0      = ws;                               // 1,600,000
    float*    f1      = f0 + (size_t)NN * 32;             // 4,800,000
    float*    n0b     = f1 + (size_t)NN * 96;             // 3,200,000
    float*    n1b     = n0b + (size_t)NN * 64;            // 9,600,000
    float*    w0T     = n1b + (size_t)NN * 192;           // 512
    float*    wpT     = w0T + 512;                        // 8192
    unsigned* counts  = (unsigned*)(wpT + 8192);          // 50,000
    unsigned* offsets = counts + NN;                      // 50,001
    unsigned* cursor  = offsets + (NN + 1);               // 50,000
    unsigned* eid     = cursor + NN;                      // 800,000
    // rec: 256B-aligned start, rest of workspace (256 SoA planes, stride CHP)
    size_t fixed_f32 = (size_t)NN * 32 + (size_t)NN * 96 + (size_t)NN * 64 +
                       (size_t)NN * 192 + 512 + 8192 + NN + (NN + 1) + NN + NE;
    size_t rec_off   = (fixed_f32 * 4 + 255) & ~(size_t)255;
    float* rec = (float*)((char*)d_ws + rec_off);

    long long avail = (long long)ws_size - (long long)rec_off;
    long long max_edges = avail / (256 * 4) - 16;
    if (max_edges < 4096) max_edges = 4096;           // last-resort floor
    int chunk = (int)((max_edges < NE) ? max_edges : NE);
    chunk &= ~255;                                    // multiple of 256
    if (chunk < 256) chunk = 256;
    int nch = (NE + chunk - 1) / chunk;
    int CHP = chunk + 16;                             // +64B: odd sector stride

    hipMemsetAsync(counts, 0, (size_t)NN * 4, stream);
    hipMemsetAsync(n0b, 0, (size_t)NN * 64 * sizeof(float), stream);
    hipMemsetAsync(n1b, 0, (size_t)NN * 192 * sizeof(float), stream);

    k_transpose<<<1, 256, 0, stream>>>(mlp_w0, wp0, wp1, wp2, wp3, w0T, wpT);
    k_node_pre<<<(NN + 7) / 8, 256, 0, stream>>>(node_s, node_v, W_feat0, W_feat1, f0, f1);
    k_hist<<<(NE + 255) / 256, 256, 0, stream>>>(edge_dst, counts);
    k_scan<<<1, 1024, 0, stream>>>(counts, offsets, cursor);
    k_fill<<<(NE + 255) / 256, 256, 0, stream>>>(edge_dst, cursor, eid);

    for (int k = 0; k < nch; k++) {
        int lo = k * chunk;
        int n  = (NE - lo < chunk) ? (NE - lo) : chunk;
        k_edgeA<<<(n + 255) / 256, 256, 0, stream>>>(lo, n, CHP, eid, edge_scalar, sh0, sh1,
                                                     edge_src, w0T, mlp_w1, wpT, f0, f1, rec);
        k_gatherB<<<(NN * 32 + 255) / 256, 256, 0, stream>>>(lo, lo + n, CHP, (k == 0) ? 1 : 0,
                                                             offsets, rec, n0b, n1b);
    }
    k_out<<<(NN + 7) / 8, 256, 0, stream>>>(node_s, node_v, W_self0, W_self1,
                                            W_out0, W_out1, n0b, n1b, (float*)d_out);
}

// Round 11
// 1930.036 us; speedup vs baseline: 2.4699x; 2.4699x over previous
//
#include <hip/hip_runtime.h>

#define NN 50000
#define NE 800000
#define MUL 32
#define RAD 8
#define FC 64

typedef float f16v __attribute__((ext_vector_type(16)));

__device__ __forceinline__ float gelu_t(float x) {
    // jax.nn.gelu approximate=True
    float x3 = x * x * x;
    float t = 0.7978845608028654f * (x + 0.044715f * x3);
    float e = __expf(2.0f * t);
    return 0.5f * x * (2.0f - 2.0f / (e + 1.0f));
}

// Pre-transpose mlp_w0 (8x64 -> 64x8) and wp0..3 (64x32 -> 4 x 32x64).
__global__ void k_transpose(const float* __restrict__ mlp_w0,
                            const float* __restrict__ wp0, const float* __restrict__ wp1,
                            const float* __restrict__ wp2, const float* __restrict__ wp3,
                            float* __restrict__ w0T, float* __restrict__ wpT) {
    int t = threadIdx.x;
    for (int idx = t; idx < FC * RAD; idx += 256) {
        int k = idx >> 3, u = idx & 7;
        w0T[idx] = mlp_w0[u * FC + k];
    }
    const float* wps[4] = {wp0, wp1, wp2, wp3};
    for (int p = 0; p < 4; p++) {
        for (int idx = t; idx < MUL * FC; idx += 256) {
            int c = idx >> 6, k = idx & 63;
            wpT[p * (MUL * FC) + idx] = wps[p][k * MUL + c];
        }
    }
}

__global__ __launch_bounds__(256) void k_node_pre(
        const float* __restrict__ node_s, const float* __restrict__ node_v,
        const float* __restrict__ W_feat0, const float* __restrict__ W_feat1,
        float* __restrict__ f0, float* __restrict__ f1) {
    __shared__ float w0[MUL * MUL], w1[MUL * MUL];
    int t = threadIdx.x;
    for (int i = t; i < MUL * MUL; i += 256) { w0[i] = W_feat0[i]; w1[i] = W_feat1[i]; }
    __syncthreads();
    int v = t & 31;
    int n = blockIdx.x * 8 + (t >> 5);
    if (n >= NN) return;
    const float invm = 0.17677669529663687f;  // 1/sqrt(32)
    float a0 = 0.f, ax = 0.f, ay = 0.f, az = 0.f;
    const float* srow = node_s + (size_t)n * MUL;
    const float* vrow = node_v + (size_t)n * MUL * 3;
#pragma unroll
    for (int u = 0; u < MUL; u++) {
        float ws = w0[u * MUL + v];
        a0 += srow[u] * ws;
        float wv = w1[u * MUL + v];
        ax += vrow[u * 3 + 0] * wv;
        ay += vrow[u * 3 + 1] * wv;
        az += vrow[u * 3 + 2] * wv;
    }
    f0[n * MUL + v] = a0 * invm;
    f1[n * 96 + v * 3 + 0] = ax * invm;
    f1[n * 96 + v * 3 + 1] = ay * invm;
    f1[n * 96 + v * 3 + 2] = az * invm;
}

// ---- CSR build: histogram -> single-block scan -> fill ----
__global__ __launch_bounds__(256) void k_hist(const int* __restrict__ edge_dst,
                                              unsigned* __restrict__ counts) {
    int e = blockIdx.x * 256 + threadIdx.x;
    if (e < NE) atomicAdd(&counts[edge_dst[e]], 1u);
}

__global__ __launch_bounds__(1024) void k_scan(const unsigned* __restrict__ counts,
                                               unsigned* __restrict__ offsets,
                                               unsigned* __restrict__ cursor) {
    __shared__ unsigned part[1024];
    int t = threadIdx.x;
    const int PER = 49;  // 49*1024 = 50176 >= 50000
    int b0 = t * PER, b1 = b0 + PER;
    if (b0 > NN) b0 = NN;
    if (b1 > NN) b1 = NN;
    unsigned s = 0;
    for (int i = b0; i < b1; i++) s += counts[i];
    part[t] = s;
    __syncthreads();
    for (int d = 1; d < 1024; d <<= 1) {
        unsigned v = (t >= d) ? part[t - d] : 0u;
        __syncthreads();
        part[t] += v;
        __syncthreads();
    }
    unsigned off = (t > 0) ? part[t - 1] : 0u;
    for (int i = b0; i < b1; i++) {
        offsets[i] = off;
        cursor[i] = off;
        off += counts[i];
    }
    if (t == 1023) offsets[NN] = part[1023];
}

__global__ __launch_bounds__(256) void k_fill(const int* __restrict__ edge_dst,
                                              unsigned* __restrict__ cursor,
                                              unsigned* __restrict__ eid) {
    int e = blockIdx.x * 256 + threadIdx.x;
    if (e < NE) {
        unsigned pos = atomicAdd(&cursor[edge_dst[e]], 1u);
        eid[pos] = (unsigned)e;
    }
}

// ---- Pass A: per-edge MLP + projections -> packed (c, edge) records ----
// rec[(c*CHP + ii)*8 + j], j: {p0, p3, p1x, p1y, p1z, p2x, p2y, p2z}
//   p0 = w0*e0*s0 ; p3 = w3*dot(e1,sh1)/sqrt3 ; p1d = (w1*e0)*sh1[d] ;
//   p2d = (w2*s0)*e1[c][d].   (1/sqrt(64) folded into w*)
// Writes: 2x float4 per c -> wave-contiguous 2KB, 64 wide stores/edge.
__global__ __launch_bounds__(256, 2) void k_edgeA(
        int lo, int n_chunk, int CHP,
        const unsigned* __restrict__ eid,
        const float* __restrict__ edge_scalar, const float* __restrict__ sh0,
        const float* __restrict__ sh1, const int* __restrict__ edge_src,
        const float* __restrict__ w0T, const float* __restrict__ mlp_w1,
        const float* __restrict__ wpT, const float* __restrict__ f0,
        const float* __restrict__ f1, float* __restrict__ rec) {
    int ii = blockIdx.x * 256 + threadIdx.x;
    if (ii >= n_chunk) return;
    int e = (int)eid[lo + ii];

    float4 xa = ((const float4*)edge_scalar)[e * 2 + 0];
    float4 xb = ((const float4*)edge_scalar)[e * 2 + 1];

    const float inv_r = 0.35355339059327373f;  // 1/sqrt(8)
    const float inv_f = 0.125f;                // 1/sqrt(64)

    f16v h0 = 0.f, h1 = 0.f, h2 = 0.f, h3 = 0.f;

    for (int k = 0; k < FC; k++) {
        const float4* w0r = (const float4*)(w0T + k * RAD);
        float4 wa = w0r[0], wb = w0r[1];
        float a = xa.x * wa.x + xa.y * wa.y + xa.z * wa.z + xa.w * wa.w +
                  xb.x * wb.x + xb.y * wb.y + xb.z * wb.z + xb.w * wb.w;
        a = gelu_t(a * inv_r);
        const float* w1r = mlp_w1 + k * FC;
#pragma unroll
        for (int i = 0; i < 16; i++) h0[i] += a * w1r[i];
#pragma unroll
        for (int i = 0; i < 16; i++) h1[i] += a * w1r[16 + i];
#pragma unroll
        for (int i = 0; i < 16; i++) h2[i] += a * w1r[32 + i];
#pragma unroll
        for (int i = 0; i < 16; i++) h3[i] += a * w1r[48 + i];
    }
#pragma unroll
    for (int i = 0; i < 16; i++) {
        h0[i] = gelu_t(h0[i] * inv_f);
        h1[i] = gelu_t(h1[i] * inv_f);
        h2[i] = gelu_t(h2[i] * inv_f);
        h3[i] = gelu_t(h3[i] * inv_f);
    }

    int src = edge_src[e];
    float s0 = sh0[e];
    float shx = sh1[e * 3 + 0], shy = sh1[e * 3 + 1], shz = sh1[e * 3 + 2];
    const float* F0 = f0 + (size_t)src * MUL;
    const float* F1 = f1 + (size_t)src * 96;
    const float inv3 = 0.5773502691896258f;  // 1/sqrt(3)

    for (int c = 0; c < MUL; c++) {
        const float* p0w = wpT + 0 * (MUL * FC) + c * FC;
        const float* p1w = wpT + 1 * (MUL * FC) + c * FC;
        const float* p2w = wpT + 2 * (MUL * FC) + c * FC;
        const float* p3w = wpT + 3 * (MUL * FC) + c * FC;
        float w0a = 0.f, w1a = 0.f, w2a = 0.f, w3a = 0.f;
#pragma unroll
        for (int i = 0; i < 16; i++) {
            float h = h0[i];
            w0a += h * p0w[i]; w1a += h * p1w[i]; w2a += h * p2w[i]; w3a += h * p3w[i];
        }
#pragma unroll
        for (int i = 0; i < 16; i++) {
            float h = h1[i];
            w0a += h * p0w[16 + i]; w1a += h * p1w[16 + i]; w2a += h * p2w[16 + i]; w3a += h * p3w[16 + i];
        }
#pragma unroll
        for (int i = 0; i < 16; i++) {
            float h = h2[i];
            w0a += h * p0w[32 + i]; w1a += h * p1w[32 + i]; w2a += h * p2w[32 + i]; w3a += h * p3w[32 + i];
        }
#pragma unroll
        for (int i = 0; i < 16; i++) {
            float h = h3[i];
            w0a += h * p0w[48 + i]; w1a += h * p1w[48 + i]; w2a += h * p2w[48 + i]; w3a += h * p3w[48 + i];
        }
        w0a *= inv_f; w1a *= inv_f; w2a *= inv_f; w3a *= inv_f;

        float e0c = F0[c];
        float e1x = F1[c * 3 + 0], e1y = F1[c * 3 + 1], e1z = F1[c * 3 + 2];
        float dot = e1x * shx + e1y * shy + e1z * shz;
        float w1e = w1a * e0c;
        float p2s = w2a * s0;

        float4 v0 = {w0a * e0c * s0, w3a * dot * inv3, w1e * shx, w1e * shy};
        float4 v1 = {w1e * shz, p2s * e1x, p2s * e1y, p2s * e1z};
        float4* out = (float4*)(rec + ((size_t)c * CHP + ii) * 8);
        out[0] = v0;
        out[1] = v1;
    }
}

// ---- Pass B: streaming segment-sum. Lane layout: consecutive lanes =
// consecutive dsts at the SAME c (adjacent CSR segments -> wave sweeps a
// contiguous region). Per edge: one 32B packed read, fully consumed. ----
__global__ __launch_bounds__(256) void k_reduceB(
        int lo, int hi, int CHP, int first, int blocks_per_c,
        const unsigned* __restrict__ offsets,
        const float* __restrict__ rec,
        float* __restrict__ n0, float* __restrict__ n1) {
    int c      = blockIdx.x / blocks_per_c;
    int dstBlk = blockIdx.x % blocks_per_c;
    int dst = dstBlk * 256 + threadIdx.x;
    if (dst >= NN) return;
    int a = (int)offsets[dst];
    int b = (int)offsets[dst + 1];
    if (a < lo) a = lo;
    if (b > hi) b = hi;
    if (a >= b) return;

    const float4* base = (const float4*)(rec + ((size_t)c * CHP - lo) * 8);

    float s_0 = 0.f, s_3 = 0.f;
    float s10 = 0.f, s11 = 0.f, s12 = 0.f;
    float s20 = 0.f, s21 = 0.f, s22 = 0.f;
    for (int i = a; i < b; i++) {
        float4 u0 = base[(size_t)i * 2 + 0];
        float4 u1 = base[(size_t)i * 2 + 1];
        s_0 += u0.x; s_3 += u0.y;
        s10 += u0.z; s11 += u0.w; s12 += u1.x;
        s20 += u1.y; s21 += u1.z; s22 += u1.w;
    }
    float* O0 = n0 + (size_t)dst * 64;
    float* O1 = n1 + (size_t)dst * 192;
    if (first) {
        O0[c]      = s_0;
        O0[32 + c] = s_3;
        O1[c * 3 + 0] = s10; O1[c * 3 + 1] = s11; O1[c * 3 + 2] = s12;
        O1[96 + c * 3 + 0] = s20; O1[96 + c * 3 + 1] = s21; O1[96 + c * 3 + 2] = s22;
    } else {
        O0[c]      += s_0;
        O0[32 + c] += s_3;
        O1[c * 3 + 0] += s10; O1[c * 3 + 1] += s11; O1[c * 3 + 2] += s12;
        O1[96 + c * 3 + 0] += s20; O1[96 + c * 3 + 1] += s21; O1[96 + c * 3 + 2] += s22;
    }
}

__global__ __launch_bounds__(256) void k_out(
        const float* __restrict__ node_s, const float* __restrict__ node_v,
        const float* __restrict__ W_self0, const float* __restrict__ W_self1,
        const float* __restrict__ W_out0, const float* __restrict__ W_out1,
        const float* __restrict__ n0, const float* __restrict__ n1,
        float* __restrict__ out) {
    __shared__ float ws0[MUL * MUL], ws1[MUL * MUL], wo0[64 * MUL], wo1[64 * MUL];
    int t = threadIdx.x;
    for (int i = t; i < MUL * MUL; i += 256) { ws0[i] = W_self0[i]; ws1[i] = W_self1[i]; }
    for (int i = t; i < 64 * MUL; i += 256) { wo0[i] = W_out0[i]; wo1[i] = W_out1[i]; }
    __syncthreads();
    int v = t & 31;
    int n = blockIdx.x * 8 + (t >> 5);
    if (n >= NN) return;
    const float invm = 0.17677669529663687f;       // 1/sqrt(32)
    const float scale_c = 0.125f * 0.25f;          // 1/sqrt(64) * 1/sqrt(16)
    const float cc = 0.9238795325112867f;          // cos(pi/8)
    const float ss = 0.3826834323650898f;          // sin(pi/8)

    float s0 = 0.f, sx = 0.f, sy = 0.f, sz = 0.f;
    const float* srow = node_s + (size_t)n * MUL;
    const float* vrow = node_v + (size_t)n * 96;
#pragma unroll
    for (int u = 0; u < MUL; u++) {
        float w = ws0[u * MUL + v];
        s0 += srow[u] * w;
        float w2 = ws1[u * MUL + v];
        sx += vrow[u * 3 + 0] * w2;
        sy += vrow[u * 3 + 1] * w2;
        sz += vrow[u * 3 + 2] * w2;
    }
    float c0 = 0.f, cx = 0.f, cy = 0.f, cz = 0.f;
    const float* nr0 = n0 + (size_t)n * 64;
    const float* nr1 = n1 + (size_t)n * 192;
#pragma unroll
    for (int u = 0; u < 64; u++) {
        float w = wo0[u * MUL + v];
        c0 += nr0[u] * w;
        float w2 = wo1[u * MUL + v];
        cx += nr1[u * 3 + 0] * w2;
        cy += nr1[u * 3 + 1] * w2;
        cz += nr1[u * 3 + 2] * w2;
    }
    float* orow = out + (size_t)n * 128;
    orow[v] = cc * s0 * invm + ss * c0 * scale_c;
    orow[32 + v * 3 + 0] = cc * sx * invm + ss * cx * scale_c;
    orow[32 + v * 3 + 1] = cc * sy * invm + ss * cy * scale_c;
    orow[32 + v * 3 + 2] = cc * sz * invm + ss * cz * scale_c;
}

extern "C" void kernel_launch(void* const* d_in, const int* in_sizes, int n_in,
                              void* d_out, int out_size, void* d_ws, size_t ws_size,
                              hipStream_t stream) {
    const float* node_s      = (const float*)d_in[0];
    const float* node_v      = (const float*)d_in[1];
    const float* sh0         = (const float*)d_in[2];
    const float* sh1         = (const float*)d_in[3];
    const float* edge_scalar = (const float*)d_in[4];
    const int*   edge_src    = (const int*)d_in[5];
    const int*   edge_dst    = (const int*)d_in[6];
    const float* W_feat0     = (const float*)d_in[7];
    const float* W_self0     = (const float*)d_in[8];
    const float* W_feat1     = (const float*)d_in[9];
    const float* W_self1     = (const float*)d_in[10];
    const float* mlp_w0      = (const float*)d_in[11];
    const float* mlp_w1      = (const float*)d_in[12];
    const float* wp0         = (const float*)d_in[13];
    const float* wp1         = (const float*)d_in[14];
    const float* wp2         = (const float*)d_in[15];
    const float* wp3         = (const float*)d_in[16];
    const float* W_out0      = (const float*)d_in[17];
    const float* W_out1      = (const float*)d_in[18];

    // workspace layout (floats/u32 are both 4B)
    float* ws  = (float*)d_ws;
    float*    f0      = ws;                               // 1,600,000
    float*    f1      = f0 + (size_t)NN * 32;             // 4,800,000
    float*    n0b     = f1 + (size_t)NN * 96;             // 3,200,000
    float*    n1b     = n0b + (size_t)NN * 64;            // 9,600,000
    float*    w0T     = n1b + (size_t)NN * 192;           // 512
    float*    wpT     = w0T + 512;                        // 8192
    unsigned* counts  = (unsigned*)(wpT + 8192);          // 50,000
    unsigned* offsets = counts + NN;                      // 50,001
    unsigned* cursor  = offsets + (NN + 1);               // 50,000
    unsigned* eid     = cursor + NN;                      // 800,000
    // rec: 256B-aligned start, rest of workspace (32 planes of 8-packed records)
    size_t fixed_f32 = (size_t)NN * 32 + (size_t)NN * 96 + (size_t)NN * 64 +
                       (size_t)NN * 192 + 512 + 8192 + NN + (NN + 1) + NN + NE;
    size_t rec_off   = (fixed_f32 * 4 + 255) & ~(size_t)255;
    float* rec = (float*)((char*)d_ws + rec_off);

    long long avail = (long long)ws_size - (long long)rec_off;
    long long max_edges = avail / (256 * 4) - 16;
    if (max_edges < 4096) max_edges = 4096;           // last-resort floor
    int chunk = (int)((max_edges < NE) ? max_edges : NE);
    chunk &= ~255;                                    // multiple of 256
    if (chunk < 256) chunk = 256;
    int nch = (NE + chunk - 1) / chunk;
    int CHP = chunk + 16;                             // pad plane stride (odd 512B)

    const int BPC = (NN + 255) / 256;                 // 196 dst-blocks per c

    hipMemsetAsync(counts, 0, (size_t)NN * 4, stream);
    hipMemsetAsync(n0b, 0, (size_t)NN * 64 * sizeof(float), stream);
    hipMemsetAsync(n1b, 0, (size_t)NN * 192 * sizeof(float), stream);

    k_transpose<<<1, 256, 0, stream>>>(mlp_w0, wp0, wp1, wp2, wp3, w0T, wpT);
    k_node_pre<<<(NN + 7) / 8, 256, 0, stream>>>(node_s, node_v, W_feat0, W_feat1, f0, f1);
    k_hist<<<(NE + 255) / 256, 256, 0, stream>>>(edge_dst, counts);
    k_scan<<<1, 1024, 0, stream>>>(counts, offsets, cursor);
    k_fill<<<(NE + 255) / 256, 256, 0, stream>>>(edge_dst, cursor, eid);

    for (int k = 0; k < nch; k++) {
        int lo = k * chunk;
        int n  = (NE - lo < chunk) ? (NE - lo) : chunk;
        k_edgeA<<<(n + 255) / 256, 256, 0, stream>>>(lo, n, CHP, eid, edge_scalar, sh0, sh1,
                                                     edge_src, w0T, mlp_w1, wpT, f0, f1, rec);
        k_reduceB<<<32 * BPC, 256, 0, stream>>>(lo, lo + n, CHP, (k == 0) ? 1 : 0, BPC,
                                                offsets, rec, n0b, n1b);
    }
    k_out<<<(NN + 7) / 8, 256, 0, stream>>>(node_s, node_v, W_self0, W_self1,
                                            W_out0, W_out1, n0b, n1b, (float*)d_out);
}